// Round 8
// baseline (320.323 us; speedup 1.0000x reference)
//
#include <hip/hip_runtime.h>

#define TPB 256

typedef __attribute__((ext_vector_type(8))) short          bf8_t;   // 8 x bf16 (4 VGPRs)
typedef __attribute__((ext_vector_type(8))) unsigned short us8_t;
typedef __attribute__((ext_vector_type(4))) float          f4_t;
typedef __attribute__((ext_vector_type(4))) unsigned short us4_t;

__device__ __forceinline__ unsigned short f2bf(float f) {
    union { float f; unsigned u; } v; v.f = f;
    unsigned r = v.u + 0x7FFFu + ((v.u >> 16) & 1u);   // round-to-nearest-even
    return (unsigned short)(r >> 16);
}
__device__ __forceinline__ float bf2f(unsigned short u) {
    union { unsigned u; float f; } v; v.u = (unsigned)u << 16; return v.f;
}

// ---------------- graph build (CSR by dst, rebuilt every call) ----------------

__global__ void k_count(const int* __restrict__ ei, int E, int* __restrict__ cnt) {
    int e = blockIdx.x * TPB + threadIdx.x;
    if (e < E) atomicAdd(&cnt[ei[E + e]], 1);
}

// fused block-sum + scan: one 512-thread block; thread t sums cnt[t*256 .. t*256+255],
// block-scans, writes exclusive per-256-chunk offsets (matches k_rowptr's block mapping).
__global__ void k_scan12(const int* __restrict__ cnt, int n, int nb, int* __restrict__ bsum) {
    __shared__ int s[512];
    int t = threadIdx.x;
    int sum = 0;
    if (t < nb) {
        int base = t * TPB;
        int end = base + TPB; if (end > n) end = n;
        for (int i = base; i < end; i++) sum += cnt[i];
    }
    s[t] = sum; __syncthreads();
    for (int off = 1; off < 512; off <<= 1) {
        int x = (t >= off) ? s[t - off] : 0;
        __syncthreads();
        s[t] += x;
        __syncthreads();
    }
    if (t < nb) bsum[t] = s[t] - sum;   // exclusive
}

__global__ void k_rowptr(const int* __restrict__ cnt, const int* __restrict__ bsum, int n, int E,
                         int* __restrict__ rowptr, int* __restrict__ cursor,
                         float* __restrict__ dinv, float* __restrict__ dis) {
    __shared__ int s[TPB];
    int t = threadIdx.x, i = blockIdx.x * TPB + t;
    int v = (i < n) ? cnt[i] : 0;
    s[t] = v; __syncthreads();
    for (int off = 1; off < TPB; off <<= 1) {
        int x = (t >= off) ? s[t - off] : 0;
        __syncthreads();
        s[t] += x;
        __syncthreads();
    }
    if (i < n) {
        int start = bsum[blockIdx.x] + s[t] - v;
        rowptr[i] = start;
        cursor[i] = start;
        float d = (float)(v + 1);      // + self loop; deg >= 1 always
        dinv[i] = 1.0f / d;
        dis[i]  = rsqrtf(d);
    }
    if (i == 0) rowptr[n] = E;
}

__global__ void k_fill(const int* __restrict__ ei, int E,
                       int* __restrict__ cursor, int* __restrict__ col) {
    int e = blockIdx.x * TPB + threadIdx.x;
    if (e < E) {
        int src = ei[e], dst = ei[E + e];
        int p = atomicAdd(&cursor[dst], 1);
        col[p] = src;
    }
}

// ---------------- weight transpose+convert: T[m*K + k] = bf16(W[k*M + m]) ----------------
__global__ void k_wconv(const float* W1, const float* Wr1, const float* W2, const float* Wr2,
                        const float* Wmu, const float* Wls,
                        unsigned short* T1, unsigned short* Tr1, unsigned short* T2,
                        unsigned short* Tr2, unsigned short* Tmu, unsigned short* Tls) {
    const float* W; unsigned short* T; int K, M;
    switch (blockIdx.y) {
        case 0: W = W1;  T = T1;  K = 128; M = 96; break;
        case 1: W = Wr1; T = Tr1; K = 128; M = 96; break;
        case 2: W = W2;  T = T2;  K = 96;  M = 64; break;
        case 3: W = Wr2; T = Tr2; K = 96;  M = 64; break;
        case 4: W = Wmu; T = Tmu; K = 64;  M = 32; break;
        default:W = Wls; T = Tls; K = 64;  M = 32; break;
    }
    int idx = blockIdx.x * TPB + threadIdx.x;
    if (idx < K * M) {
        int m = idx / K, k = idx % K;
        T[idx] = f2bf(W[k * M + m]);
    }
}

// ---------------- MFMA GEMM (r0-measured-best form): LDS-staged B, 64-row tiles ------------
template <int K, int M, bool AF32>
__global__ __launch_bounds__(TPB) void k_gemm3(const void* __restrict__ Av,
                                               const unsigned short* __restrict__ WT,
                                               unsigned short* __restrict__ Yb,
                                               int n, int nt) {
    constexpr int KS = K / 32;
    constexpr int ST = K + 8;
    __shared__ unsigned short Bs[M * ST];
    for (int i = threadIdx.x * 8; i < M * K; i += TPB * 8) {
        int m = i / K, k = i - m * K;
        *(us8_t*)(Bs + m * ST + k) = *(const us8_t*)(WT + i);
    }
    __syncthreads();

    int lane = threadIdx.x & 63;
    int wave = threadIdx.x >> 6;
    int quad = lane >> 4;
    int l15  = lane & 15;

    for (int tile = blockIdx.x; tile < nt; tile += gridDim.x) {
        int base = tile * 64 + wave * 16;
        int rA = base + l15; if (rA > n - 1) rA = n - 1;

        bf8_t a[KS];
        if (AF32) {
            const float* ap = (const float*)Av + (size_t)rA * K + quad * 8;
#pragma unroll
            for (int s = 0; s < KS; s++) {
                f4_t lo = *(const f4_t*)(ap + s * 32);
                f4_t hi = *(const f4_t*)(ap + s * 32 + 4);
                bf8_t t;
                t[0] = (short)f2bf(lo.x); t[1] = (short)f2bf(lo.y);
                t[2] = (short)f2bf(lo.z); t[3] = (short)f2bf(lo.w);
                t[4] = (short)f2bf(hi.x); t[5] = (short)f2bf(hi.y);
                t[6] = (short)f2bf(hi.z); t[7] = (short)f2bf(hi.w);
                a[s] = t;
            }
        } else {
            const unsigned short* ap = (const unsigned short*)Av + (size_t)rA * K + quad * 8;
#pragma unroll
            for (int s = 0; s < KS; s++) a[s] = *(const bf8_t*)(ap + s * 32);
        }

        int row = base + quad * 4;
#pragma unroll
        for (int ct = 0; ct < M / 16; ct++) {
            const unsigned short* bp = Bs + (ct * 16 + l15) * ST + quad * 8;
            f4_t acc = {0.f, 0.f, 0.f, 0.f};
#pragma unroll
            for (int s = 0; s < KS; s++) {
                bf8_t b = *(const bf8_t*)(bp + s * 32);
                acc = __builtin_amdgcn_mfma_f32_16x16x32_bf16(a[s], b, acc, 0, 0, 0);
            }
            int colg = ct * 16 + l15;
#pragma unroll
            for (int r = 0; r < 4; r++) {
                if (row + r < n) Yb[(size_t)(row + r) * M + colg] = f2bf(acc[r]);
            }
        }
    }
}

// 2-way edge-split gather body (macro-free, inlined per kernel):
// half eh walks edges r0+eh, r0+eh+2, ... ; partials combined via one shfl_xor per elem.

// ---------------- fuse1: agg(layer1) + GEMM(layer2), 2-way split gather ---------------------
// Phase 1: 32 lanes/node (eh = lane>>4 edge-half, 12 of 16 col-lanes active), 2 passes of
// 8 rows -> LDS. Phase 2 unchanged (W2 slices in regs, 16x128 MFMA).
__global__ __launch_bounds__(TPB, 4) void k_fuse1(const unsigned short* __restrict__ AB,
                                                  const unsigned short* __restrict__ WT2,
                                                  const float* __restrict__ bias,
                                                  const float* __restrict__ dinv,
                                                  const int* __restrict__ rowptr,
                                                  const int* __restrict__ col,
                                                  unsigned short* __restrict__ AB2,
                                                  int n, int nt) {
    constexpr int LDA = 192, MF = 96, ST1 = 104, KS = 3, M2 = 128;
    __shared__ unsigned short Hs[2][16 * ST1];

    int t = threadIdx.x;
    int lane = t & 63, wave = t >> 6, quad = lane >> 4, l15 = lane & 15;

    bf8_t breg[2][KS];
#pragma unroll
    for (int j = 0; j < 2; j++) {
        const unsigned short* bp = WT2 + (size_t)((wave * 2 + j) * 16 + l15) * 96 + quad * 8;
#pragma unroll
        for (int s = 0; s < KS; s++) breg[j][s] = *(const bf8_t*)(bp + s * 32);
    }

    int u   = t & 31;          // within node-group
    int eh  = u >> 4;          // edge half 0/1
    int cg  = u & 15;
    int c   = cg * 8;
    bool act = (c < MF);
    int slot = t >> 5;         // 0..7

    int p = 0;
    for (int tile = blockIdx.x; tile < nt; tile += gridDim.x, p ^= 1) {
        int tbase = tile * 16;
#pragma unroll
        for (int pp = 0; pp < 2; pp++) {
            int gl = pp * 8 + slot;
            int g = tbase + gl; if (g > n - 1) g = n - 1;
            float acc[8];
#pragma unroll
            for (int j = 0; j < 8; j++) acc[j] = 0.f;
            if (act) {
                if (eh == 0) {
                    bf8_t v = *(const bf8_t*)(AB + (size_t)g * LDA + c);
#pragma unroll
                    for (int j = 0; j < 8; j++) acc[j] = bf2f((unsigned short)v[j]);
                }
                int r0 = rowptr[g], r1 = rowptr[g + 1];
                int e = r0 + eh;
                for (; e + 6 < r1; e += 8) {
                    int s0 = col[e], s1 = col[e + 2], s2 = col[e + 4], s3 = col[e + 6];
                    bf8_t v0 = *(const bf8_t*)(AB + (size_t)s0 * LDA + c);
                    bf8_t v1 = *(const bf8_t*)(AB + (size_t)s1 * LDA + c);
                    bf8_t v2 = *(const bf8_t*)(AB + (size_t)s2 * LDA + c);
                    bf8_t v3 = *(const bf8_t*)(AB + (size_t)s3 * LDA + c);
#pragma unroll
                    for (int j = 0; j < 8; j++)
                        acc[j] += (bf2f((unsigned short)v0[j]) + bf2f((unsigned short)v1[j]))
                                + (bf2f((unsigned short)v2[j]) + bf2f((unsigned short)v3[j]));
                }
                for (; e < r1; e += 2) {
                    int s = col[e];
                    bf8_t v = *(const bf8_t*)(AB + (size_t)s * LDA + c);
#pragma unroll
                    for (int j = 0; j < 8; j++) acc[j] += bf2f((unsigned short)v[j]);
                }
            }
            // combine halves: partner lane = t ^ 16 (same wave)
#pragma unroll
            for (int j = 0; j < 8; j++) acc[j] += __shfl_xor(acc[j], 16, 64);
            if (act && eh == 0) {
                float di = dinv[g];
                bf8_t rr = *(const bf8_t*)(AB + (size_t)g * LDA + MF + c);
                us8_t o;
#pragma unroll
                for (int j = 0; j < 8; j++)
                    o[j] = f2bf(fmaxf(acc[j] * di + bf2f((unsigned short)rr[j]) + bias[c + j], 0.f));
                *(us8_t*)(&Hs[p][gl * ST1 + c]) = o;
            }
        }
        __syncthreads();

        // phase 2: 16 x 128 GEMM from LDS h1 tile
        int row = tbase + quad * 4;
#pragma unroll
        for (int j = 0; j < 2; j++) {
            const unsigned short* apl = &Hs[p][l15 * ST1 + quad * 8];
            f4_t acc2 = {0.f, 0.f, 0.f, 0.f};
#pragma unroll
            for (int s = 0; s < KS; s++) {
                bf8_t a = *(const bf8_t*)(apl + s * 32);
                acc2 = __builtin_amdgcn_mfma_f32_16x16x32_bf16(a, breg[j][s], acc2, 0, 0, 0);
            }
            int colg = (wave * 2 + j) * 16 + l15;
#pragma unroll
            for (int r = 0; r < 4; r++) {
                if (row + r < n) AB2[(size_t)(row + r) * M2 + colg] = f2bf(acc2[r]);
            }
        }
    }
}

// ---------------- aggc2 (layer 2): 2-way split gather, 16 nodes/block ------------------------
// H2s[g] = dis * relu(dinv*agg(y2) + r2 + b2)
__global__ __launch_bounds__(TPB) void k_aggc2(const unsigned short* __restrict__ AB,
                                               const float* __restrict__ bias,
                                               const float* __restrict__ dinv,
                                               const float* __restrict__ dis,
                                               const int* __restrict__ rowptr,
                                               const int* __restrict__ col,
                                               unsigned short* __restrict__ Hb, int n) {
    constexpr int MF = 64, LD = 128;
    int t = threadIdx.x;
    int g = blockIdx.x * 16 + (t >> 4);
    if (g >= n) return;                    // group-uniform; no barriers in kernel
    int u  = t & 15;
    int eh = u >> 3;
    int c  = (u & 7) * 8;
    int r0 = rowptr[g], r1 = rowptr[g + 1];
    float acc[8];
#pragma unroll
    for (int j = 0; j < 8; j++) acc[j] = 0.f;
    if (eh == 0) {
        bf8_t v = *(const bf8_t*)(AB + (size_t)g * LD + c);
#pragma unroll
        for (int j = 0; j < 8; j++) acc[j] = bf2f((unsigned short)v[j]);
    }
    int e = r0 + eh;
    for (; e + 6 < r1; e += 8) {
        int s0 = col[e], s1 = col[e + 2], s2 = col[e + 4], s3 = col[e + 6];
        bf8_t v0 = *(const bf8_t*)(AB + (size_t)s0 * LD + c);
        bf8_t v1 = *(const bf8_t*)(AB + (size_t)s1 * LD + c);
        bf8_t v2 = *(const bf8_t*)(AB + (size_t)s2 * LD + c);
        bf8_t v3 = *(const bf8_t*)(AB + (size_t)s3 * LD + c);
#pragma unroll
        for (int j = 0; j < 8; j++)
            acc[j] += (bf2f((unsigned short)v0[j]) + bf2f((unsigned short)v1[j]))
                    + (bf2f((unsigned short)v2[j]) + bf2f((unsigned short)v3[j]));
    }
    for (; e < r1; e += 2) {
        int s = col[e];
        bf8_t v = *(const bf8_t*)(AB + (size_t)s * LD + c);
#pragma unroll
        for (int j = 0; j < 8; j++) acc[j] += bf2f((unsigned short)v[j]);
    }
#pragma unroll
    for (int j = 0; j < 8; j++) acc[j] += __shfl_xor(acc[j], 8, 64);
    if (eh == 0) {
        float di = dinv[g], sc = dis[g];
        bf8_t rr = *(const bf8_t*)(AB + (size_t)g * LD + MF + c);
        us8_t o;
#pragma unroll
        for (int j = 0; j < 8; j++) {
            float h = fmaxf(acc[j] * di + bf2f((unsigned short)rr[j]) + bias[c + j], 0.f);
            o[j] = f2bf(sc * h);
        }
        *(us8_t*)(Hb + (size_t)g * MF + c) = o;
    }
}

// ---------------- fuse2: head agg (2-way split) + head GEMM per 32-row tile -----------------
__global__ __launch_bounds__(TPB, 4) void k_fuse2(const unsigned short* __restrict__ H2s,
                                                  const unsigned short* __restrict__ WTo,
                                                  const float* __restrict__ bmu,
                                                  const float* __restrict__ bls,
                                                  const float* __restrict__ dis,
                                                  const int* __restrict__ rowptr,
                                                  const int* __restrict__ col,
                                                  float* __restrict__ out, int n, int nt) {
    constexpr int ST2 = 72, KS = 2;
    __shared__ unsigned short Zs[2][32 * ST2];

    int t = threadIdx.x;
    int lane = t & 63, wave = t >> 6, quad = lane >> 4, l15 = lane & 15;

    bf8_t breg[KS];
    {
        const unsigned short* bp = WTo + (size_t)(wave * 16 + l15) * 64 + quad * 8;
#pragma unroll
        for (int s = 0; s < KS; s++) breg[s] = *(const bf8_t*)(bp + s * 32);
    }
    int colg = wave * 16 + l15;
    float bias = (colg < 32) ? bmu[colg] : bls[colg - 32];
    float* dstc = (colg < 32) ? (out + colg) : (out + (size_t)n * 32 + (colg - 32));

    int u  = t & 15;
    int eh = u >> 3;
    int c  = (u & 7) * 8;
    int slot = t >> 4;        // 0..15

    int p = 0;
    for (int tile = blockIdx.x; tile < nt; tile += gridDim.x, p ^= 1) {
        int tbase = tile * 32;
#pragma unroll
        for (int pp = 0; pp < 2; pp++) {
            int gl = pp * 16 + slot;
            int g = tbase + gl; if (g > n - 1) g = n - 1;
            float acc[8];
#pragma unroll
            for (int j = 0; j < 8; j++) acc[j] = 0.f;
            if (eh == 0) {
                bf8_t v = *(const bf8_t*)(H2s + (size_t)g * 64 + c);
#pragma unroll
                for (int j = 0; j < 8; j++) acc[j] = bf2f((unsigned short)v[j]);
            }
            int r0 = rowptr[g], r1 = rowptr[g + 1];
            int e = r0 + eh;
            for (; e + 6 < r1; e += 8) {
                int s0 = col[e], s1 = col[e + 2], s2 = col[e + 4], s3 = col[e + 6];
                bf8_t v0 = *(const bf8_t*)(H2s + (size_t)s0 * 64 + c);
                bf8_t v1 = *(const bf8_t*)(H2s + (size_t)s1 * 64 + c);
                bf8_t v2 = *(const bf8_t*)(H2s + (size_t)s2 * 64 + c);
                bf8_t v3 = *(const bf8_t*)(H2s + (size_t)s3 * 64 + c);
#pragma unroll
                for (int j = 0; j < 8; j++)
                    acc[j] += (bf2f((unsigned short)v0[j]) + bf2f((unsigned short)v1[j]))
                            + (bf2f((unsigned short)v2[j]) + bf2f((unsigned short)v3[j]));
            }
            for (; e < r1; e += 2) {
                int s = col[e];
                bf8_t v = *(const bf8_t*)(H2s + (size_t)s * 64 + c);
#pragma unroll
                for (int j = 0; j < 8; j++) acc[j] += bf2f((unsigned short)v[j]);
            }
#pragma unroll
            for (int j = 0; j < 8; j++) acc[j] += __shfl_xor(acc[j], 8, 64);
            if (eh == 0) {
                float dg = dis[g];
                us8_t o;
#pragma unroll
                for (int j = 0; j < 8; j++) o[j] = f2bf(dg * acc[j]);
                *(us8_t*)(&Zs[p][gl * ST2 + c]) = o;
            }
        }
        __syncthreads();

#pragma unroll
        for (int st = 0; st < 2; st++) {
            const unsigned short* apl = &Zs[p][(st * 16 + l15) * ST2 + quad * 8];
            bf8_t a[KS];
#pragma unroll
            for (int s = 0; s < KS; s++) a[s] = *(const bf8_t*)(apl + s * 32);
            f4_t acc = {0.f, 0.f, 0.f, 0.f};
#pragma unroll
            for (int s = 0; s < KS; s++)
                acc = __builtin_amdgcn_mfma_f32_16x16x32_bf16(a[s], breg[s], acc, 0, 0, 0);
            int row = tbase + st * 16 + quad * 4;
#pragma unroll
            for (int r = 0; r < 4; r++) {
                if (row + r < n) dstc[(size_t)(row + r) * 32] = acc[r] + bias;
            }
        }
    }
}

// ---------------- launch ----------------

extern "C" void kernel_launch(void* const* d_in, const int* in_sizes, int n_in,
                              void* d_out, int out_size, void* d_ws, size_t ws_size,
                              hipStream_t stream) {
    const float* x   = (const float*)d_in[0];
    const int*   ei  = (const int*)d_in[1];
    const float* W1  = (const float*)d_in[2];
    const float* b1  = (const float*)d_in[3];
    const float* Wr1 = (const float*)d_in[4];
    const float* W2  = (const float*)d_in[5];
    const float* b2  = (const float*)d_in[6];
    const float* Wr2 = (const float*)d_in[7];
    const float* Wmu = (const float*)d_in[8];
    const float* bmu = (const float*)d_in[9];
    const float* Wls = (const float*)d_in[10];
    const float* bls = (const float*)d_in[11];
    float* out = (float*)d_out;

    const int IN = 128, L1F = 96, L2F = 64;
    const int N = in_sizes[0] / IN;
    const int E = in_sizes[1] / 2;

    char* ws = (char*)d_ws;
    size_t off = 0;
    auto alloc = [&](size_t b) { size_t r = off; off += (b + 255) & ~(size_t)255; return r; };

    const int nb = (N + TPB - 1) / TPB;
    int*   cnt  = (int*)(ws + alloc((size_t)N * 4));
    int*   bsum = (int*)(ws + alloc((size_t)nb * 4));
    int*   rowp = (int*)(ws + alloc((size_t)(N + 1) * 4));
    int*   curs = (int*)(ws + alloc((size_t)N * 4));
    int*   col  = (int*)(ws + alloc((size_t)E * 4));
    float* dinv = (float*)(ws + alloc((size_t)N * 4));
    float* dis  = (float*)(ws + alloc((size_t)N * 4));
    unsigned short* T1  = (unsigned short*)(ws + alloc((size_t)IN  * L1F * 2));
    unsigned short* Tr1 = (unsigned short*)(ws + alloc((size_t)IN  * L1F * 2));
    unsigned short* T2  = (unsigned short*)(ws + alloc((size_t)L1F * L2F * 2));
    unsigned short* Tr2 = (unsigned short*)(ws + alloc((size_t)L1F * L2F * 2));
    unsigned short* Tmu = (unsigned short*)(ws + alloc((size_t)L2F * 32 * 2));
    unsigned short* Tls = (unsigned short*)(ws + alloc((size_t)L2F * 32 * 2));
    unsigned short* AB1 = (unsigned short*)(ws + alloc((size_t)N * 2 * L1F * 2)); // N x 192 bf16
    unsigned short* AB2 = (unsigned short*)(ws + alloc((size_t)N * 2 * L2F * 2)); // N x 128 bf16
    unsigned short* H2s = (unsigned short*)(ws + alloc((size_t)N * L2F * 2));     // dis-scaled h2
    (void)Tr1; (void)Tr2; (void)Tls;

    hipMemsetAsync(cnt, 0, (size_t)N * 4, stream);

    dim3 eg((E + TPB - 1) / TPB);
    k_count<<<eg, TPB, 0, stream>>>(ei, E, cnt);
    k_scan12<<<1, 512, 0, stream>>>(cnt, N, nb, bsum);
    k_rowptr<<<nb, TPB, 0, stream>>>(cnt, bsum, N, E, rowp, curs, dinv, dis);
    k_fill<<<eg, TPB, 0, stream>>>(ei, E, curs, col);

    k_wconv<<<dim3(48, 6), TPB, 0, stream>>>(W1, Wr1, W2, Wr2, Wmu, Wls,
                                             T1, Tr1, T2, Tr2, Tmu, Tls);

    // layer 1 GEMM: AB1 = x @ [W1|Wr1]  (r0-measured-best config)
    const int nt64 = (N + 63) / 64;
    k_gemm3<128, 192, true><<<768, TPB, 0, stream>>>(x, T1, AB1, N, nt64);

    // fused: agg(layer1) + GEMM(layer2) -> AB2
    const int nt16 = (N + 15) / 16;
    k_fuse1<<<2048, TPB, 0, stream>>>(AB1, T2, b1, dinv, rowp, col, AB2, N, nt16);

    // layer 2 aggregation: H2s = dis * relu(dinv*agg + r + b2)
    k_aggc2<<<(N + 15) / 16, TPB, 0, stream>>>(AB2, b2, dinv, dis, rowp, col, H2s, N);

    // fused: head aggregation + head GEMM -> out
    const int nt32 = (N + 31) / 32;
    k_fuse2<<<2048, TPB, 0, stream>>>(H2s, Tmu, bmu, bls, dis, rowp, col, out, N, nt32);
}

// Round 9
// 289.797 us; speedup vs baseline: 1.1053x; 1.1053x over previous
//
#include <hip/hip_runtime.h>

#define TPB 256

typedef __attribute__((ext_vector_type(8))) short          bf8_t;   // 8 x bf16 (4 VGPRs)
typedef __attribute__((ext_vector_type(8))) unsigned short us8_t;
typedef __attribute__((ext_vector_type(4))) float          f4_t;
typedef __attribute__((ext_vector_type(4))) unsigned short us4_t;
typedef __attribute__((ext_vector_type(4))) int            i4_t;

__device__ __forceinline__ unsigned short f2bf(float f) {
    union { float f; unsigned u; } v; v.f = f;
    unsigned r = v.u + 0x7FFFu + ((v.u >> 16) & 1u);   // round-to-nearest-even
    return (unsigned short)(r >> 16);
}
__device__ __forceinline__ float bf2f(unsigned short u) {
    union { unsigned u; float f; } v; v.u = (unsigned)u << 16; return v.f;
}

// ---------------- graph build (CSR by dst, rebuilt every call) ----------------

__global__ void k_count(const int* __restrict__ ei, int E, int* __restrict__ cnt) {
    int e = blockIdx.x * TPB + threadIdx.x;
    if (e < E) atomicAdd(&cnt[ei[E + e]], 1);
}

// fused block-sum + scan, int4-vectorized partial sums.
__global__ void k_scan12(const int* __restrict__ cnt, int n, int nb, int* __restrict__ bsum) {
    __shared__ int s[512];
    int t = threadIdx.x;
    int sum = 0;
    if (t < nb) {
        int base = t * TPB;
        int end = base + TPB; if (end > n) end = n;
        int i = base;
        for (; i + 4 <= end; i += 4) {
            i4_t v = *(const i4_t*)(cnt + i);
            sum += v.x + v.y + v.z + v.w;
        }
        for (; i < end; i++) sum += cnt[i];
    }
    s[t] = sum; __syncthreads();
    for (int off = 1; off < 512; off <<= 1) {
        int x = (t >= off) ? s[t - off] : 0;
        __syncthreads();
        s[t] += x;
        __syncthreads();
    }
    if (t < nb) bsum[t] = s[t] - sum;   // exclusive
}

__global__ void k_rowptr(const int* __restrict__ cnt, const int* __restrict__ bsum, int n, int E,
                         int* __restrict__ rowptr, int* __restrict__ cursor,
                         float* __restrict__ dinv, float* __restrict__ dis) {
    __shared__ int s[TPB];
    int t = threadIdx.x, i = blockIdx.x * TPB + t;
    int v = (i < n) ? cnt[i] : 0;
    s[t] = v; __syncthreads();
    for (int off = 1; off < TPB; off <<= 1) {
        int x = (t >= off) ? s[t - off] : 0;
        __syncthreads();
        s[t] += x;
        __syncthreads();
    }
    if (i < n) {
        int start = bsum[blockIdx.x] + s[t] - v;
        rowptr[i] = start;
        cursor[i] = start;
        float d = (float)(v + 1);      // + self loop; deg >= 1 always
        dinv[i] = 1.0f / d;
        dis[i]  = rsqrtf(d);
    }
    if (i == 0) rowptr[n] = E;
}

__global__ void k_fill(const int* __restrict__ ei, int E,
                       int* __restrict__ cursor, int* __restrict__ col) {
    int e = blockIdx.x * TPB + threadIdx.x;
    if (e < E) {
        int src = ei[e], dst = ei[E + e];
        int p = atomicAdd(&cursor[dst], 1);
        col[p] = src;
    }
}

// ---------------- weight transpose+convert: T[m*K + k] = bf16(W[k*M + m]) ----------------
__global__ void k_wconv(const float* W1, const float* Wr1, const float* W2, const float* Wr2,
                        const float* Wmu, const float* Wls,
                        unsigned short* T1, unsigned short* Tr1, unsigned short* T2,
                        unsigned short* Tr2, unsigned short* Tmu, unsigned short* Tls) {
    const float* W; unsigned short* T; int K, M;
    switch (blockIdx.y) {
        case 0: W = W1;  T = T1;  K = 128; M = 96; break;
        case 1: W = Wr1; T = Tr1; K = 128; M = 96; break;
        case 2: W = W2;  T = T2;  K = 96;  M = 64; break;
        case 3: W = Wr2; T = Tr2; K = 96;  M = 64; break;
        case 4: W = Wmu; T = Tmu; K = 64;  M = 32; break;
        default:W = Wls; T = Tls; K = 64;  M = 32; break;
    }
    int idx = blockIdx.x * TPB + threadIdx.x;
    if (idx < K * M) {
        int m = idx / K, k = idx % K;
        T[idx] = f2bf(W[k * M + m]);
    }
}

// ---------------- MFMA GEMM (r0-measured-best form) with SPLIT outputs ----------------------
// Writes cols [0,MH) to Yb (stride MH) and [MH,M) to Rb (stride M-MH). Store pattern per
// row identical to the proven amp-1.0 epilogue; only the base pointer differs per ct
// (compile-time). Split lets the downstream random gather touch only the 19.2-MB Y buffer.
template <int K, int M, int MH, bool AF32>
__global__ __launch_bounds__(TPB) void k_gemm3s(const void* __restrict__ Av,
                                                const unsigned short* __restrict__ WT,
                                                unsigned short* __restrict__ Yb,
                                                unsigned short* __restrict__ Rb,
                                                int n, int nt) {
    constexpr int KS = K / 32;
    constexpr int ST = K + 8;
    __shared__ unsigned short Bs[M * ST];
    for (int i = threadIdx.x * 8; i < M * K; i += TPB * 8) {
        int m = i / K, k = i - m * K;
        *(us8_t*)(Bs + m * ST + k) = *(const us8_t*)(WT + i);
    }
    __syncthreads();

    int lane = threadIdx.x & 63;
    int wave = threadIdx.x >> 6;
    int quad = lane >> 4;
    int l15  = lane & 15;

    for (int tile = blockIdx.x; tile < nt; tile += gridDim.x) {
        int base = tile * 64 + wave * 16;
        int rA = base + l15; if (rA > n - 1) rA = n - 1;

        bf8_t a[KS];
        if (AF32) {
            const float* ap = (const float*)Av + (size_t)rA * K + quad * 8;
#pragma unroll
            for (int s = 0; s < KS; s++) {
                f4_t lo = *(const f4_t*)(ap + s * 32);
                f4_t hi = *(const f4_t*)(ap + s * 32 + 4);
                bf8_t t;
                t[0] = (short)f2bf(lo.x); t[1] = (short)f2bf(lo.y);
                t[2] = (short)f2bf(lo.z); t[3] = (short)f2bf(lo.w);
                t[4] = (short)f2bf(hi.x); t[5] = (short)f2bf(hi.y);
                t[6] = (short)f2bf(hi.z); t[7] = (short)f2bf(hi.w);
                a[s] = t;
            }
        } else {
            const unsigned short* ap = (const unsigned short*)Av + (size_t)rA * K + quad * 8;
#pragma unroll
            for (int s = 0; s < KS; s++) a[s] = *(const bf8_t*)(ap + s * 32);
        }

        int row = base + quad * 4;
#pragma unroll
        for (int ct = 0; ct < M / 16; ct++) {
            const unsigned short* bp = Bs + (ct * 16 + l15) * ST + quad * 8;
            f4_t acc = {0.f, 0.f, 0.f, 0.f};
#pragma unroll
            for (int s = 0; s < KS; s++) {
                bf8_t b = *(const bf8_t*)(bp + s * 32);
                acc = __builtin_amdgcn_mfma_f32_16x16x32_bf16(a[s], b, acc, 0, 0, 0);
            }
            int colg = ct * 16 + l15;
            unsigned short* dst;
            if (ct * 16 < MH) dst = Yb + (size_t)0 * MH + colg;          // col in Y half
            else              dst = Rb + (colg - MH);                     // col in R half
            constexpr int SY = MH, SR = M - MH;
            int stride = (ct * 16 < MH) ? SY : SR;
#pragma unroll
            for (int r = 0; r < 4; r++) {
                if (row + r < n) dst[(size_t)(row + r) * stride] = f2bf(acc[r]);
            }
        }
    }
}

// ---------------- fuse1: agg(layer1) + GEMM(layer2) per 16-row tile (r7 gather body) --------
// Gather reads Y1 (N x 96, 19.2 MB working set — was 38.4 as [y|r] rows); residual from R1.
// Phase 2: split writes Y2 / R2 (wave 0/1 -> Y2 cols, wave 2/3 -> R2 cols; wave-uniform).
__global__ __launch_bounds__(TPB, 4) void k_fuse1(const unsigned short* __restrict__ Y1,
                                                  const unsigned short* __restrict__ R1,
                                                  const unsigned short* __restrict__ WT2,
                                                  const float* __restrict__ bias,
                                                  const float* __restrict__ dinv,
                                                  const int* __restrict__ rowptr,
                                                  const int* __restrict__ col,
                                                  unsigned short* __restrict__ Y2,
                                                  unsigned short* __restrict__ R2,
                                                  int n, int nt) {
    constexpr int MF = 96, ST1 = 104, KS = 3;
    __shared__ unsigned short Hs[2][16 * ST1];

    int t = threadIdx.x;
    int lane = t & 63, wave = t >> 6, quad = lane >> 4, l15 = lane & 15;

    bf8_t breg[2][KS];
#pragma unroll
    for (int j = 0; j < 2; j++) {
        const unsigned short* bp = WT2 + (size_t)((wave * 2 + j) * 16 + l15) * 96 + quad * 8;
#pragma unroll
        for (int s = 0; s < KS; s++) breg[j][s] = *(const bf8_t*)(bp + s * 32);
    }

    int gl = t >> 4;          // tile-local row 0..15
    int cg = t & 15;          // col-group; active if cg < 12
    int c  = cg * 8;
    bool p1act = (c < MF);

    int p = 0;
    for (int tile = blockIdx.x; tile < nt; tile += gridDim.x, p ^= 1) {
        int tbase = tile * 16;
        if (p1act) {
            int g = tbase + gl; if (g > n - 1) g = n - 1;
            int r0 = rowptr[g], r1 = rowptr[g + 1];
            float acc[8];
            {
                bf8_t v = *(const bf8_t*)(Y1 + (size_t)g * MF + c);
#pragma unroll
                for (int j = 0; j < 8; j++) acc[j] = bf2f((unsigned short)v[j]);
            }
            int e = r0;
            for (; e + 4 <= r1; e += 4) {
                int s0 = col[e], s1 = col[e + 1], s2 = col[e + 2], s3 = col[e + 3];
                bf8_t v0 = *(const bf8_t*)(Y1 + (size_t)s0 * MF + c);
                bf8_t v1 = *(const bf8_t*)(Y1 + (size_t)s1 * MF + c);
                bf8_t v2 = *(const bf8_t*)(Y1 + (size_t)s2 * MF + c);
                bf8_t v3 = *(const bf8_t*)(Y1 + (size_t)s3 * MF + c);
#pragma unroll
                for (int j = 0; j < 8; j++)
                    acc[j] += (bf2f((unsigned short)v0[j]) + bf2f((unsigned short)v1[j]))
                            + (bf2f((unsigned short)v2[j]) + bf2f((unsigned short)v3[j]));
            }
            for (; e < r1; ++e) {
                int s = col[e];
                bf8_t v = *(const bf8_t*)(Y1 + (size_t)s * MF + c);
#pragma unroll
                for (int j = 0; j < 8; j++) acc[j] += bf2f((unsigned short)v[j]);
            }
            float di = dinv[g];
            bf8_t rr = *(const bf8_t*)(R1 + (size_t)g * MF + c);
            us8_t o;
#pragma unroll
            for (int j = 0; j < 8; j++)
                o[j] = f2bf(fmaxf(acc[j] * di + bf2f((unsigned short)rr[j]) + bias[c + j], 0.f));
            *(us8_t*)(&Hs[p][gl * ST1 + c]) = o;
        }
        __syncthreads();

        // phase 2: 16 x 128 GEMM from LDS h1 tile; cols 0-63 -> Y2, 64-127 -> R2
        int row = tbase + quad * 4;
#pragma unroll
        for (int j = 0; j < 2; j++) {
            const unsigned short* apl = &Hs[p][l15 * ST1 + quad * 8];
            f4_t acc2 = {0.f, 0.f, 0.f, 0.f};
#pragma unroll
            for (int s = 0; s < KS; s++) {
                bf8_t a = *(const bf8_t*)(apl + s * 32);
                acc2 = __builtin_amdgcn_mfma_f32_16x16x32_bf16(a, breg[j][s], acc2, 0, 0, 0);
            }
            int colg = (wave * 2 + j) * 16 + l15;
            unsigned short* dst = (colg < 64) ? (Y2 + colg) : (R2 + (colg - 64));
#pragma unroll
            for (int r = 0; r < 4; r++) {
                if (row + r < n) dst[(size_t)(row + r) * 64] = f2bf(acc2[r]);
            }
        }
    }
}

// ---------------- aggc2 (layer 2, r7 body): H2s = dis * relu(dinv*agg(Y2) + R2 + b2) --------
// Y2 rows are 128 B and 128-B aligned -> exactly 1 cache line per gathered edge.
__global__ __launch_bounds__(TPB) void k_aggc2(const unsigned short* __restrict__ Y2,
                                               const unsigned short* __restrict__ R2,
                                               const float* __restrict__ bias,
                                               const float* __restrict__ dinv,
                                               const float* __restrict__ dis,
                                               const int* __restrict__ rowptr,
                                               const int* __restrict__ col,
                                               unsigned short* __restrict__ Hb, int n) {
    constexpr int MF = 64, GRP = 8;
    int g = blockIdx.x * (TPB / GRP) + threadIdx.x / GRP;
    if (g >= n) return;
    int c = (threadIdx.x & (GRP - 1)) * 8;
    int r0 = rowptr[g], r1 = rowptr[g + 1];
    float acc[8];
    {
        bf8_t v = *(const bf8_t*)(Y2 + (size_t)g * MF + c);
#pragma unroll
        for (int j = 0; j < 8; j++) acc[j] = bf2f((unsigned short)v[j]);
    }
    int e = r0;
    for (; e + 4 <= r1; e += 4) {
        int s0 = col[e], s1 = col[e + 1], s2 = col[e + 2], s3 = col[e + 3];
        bf8_t v0 = *(const bf8_t*)(Y2 + (size_t)s0 * MF + c);
        bf8_t v1 = *(const bf8_t*)(Y2 + (size_t)s1 * MF + c);
        bf8_t v2 = *(const bf8_t*)(Y2 + (size_t)s2 * MF + c);
        bf8_t v3 = *(const bf8_t*)(Y2 + (size_t)s3 * MF + c);
#pragma unroll
        for (int j = 0; j < 8; j++)
            acc[j] += (bf2f((unsigned short)v0[j]) + bf2f((unsigned short)v1[j]))
                    + (bf2f((unsigned short)v2[j]) + bf2f((unsigned short)v3[j]));
    }
    for (; e < r1; ++e) {
        int s = col[e];
        bf8_t v = *(const bf8_t*)(Y2 + (size_t)s * MF + c);
#pragma unroll
        for (int j = 0; j < 8; j++) acc[j] += bf2f((unsigned short)v[j]);
    }
    float di = dinv[g], sc = dis[g];
    bf8_t rr = *(const bf8_t*)(R2 + (size_t)g * MF + c);
    us8_t o;
#pragma unroll
    for (int j = 0; j < 8; j++) {
        float h = fmaxf(acc[j] * di + bf2f((unsigned short)rr[j]) + bias[c + j], 0.f);
        o[j] = f2bf(sc * h);
    }
    *(us8_t*)(Hb + (size_t)g * MF + c) = o;
}

// ---------------- fuse2 (r7 body): head agg + head GEMM per 32-row tile ---------------------
__global__ __launch_bounds__(TPB, 4) void k_fuse2(const unsigned short* __restrict__ H2s,
                                                  const unsigned short* __restrict__ WTo,
                                                  const float* __restrict__ bmu,
                                                  const float* __restrict__ bls,
                                                  const float* __restrict__ dis,
                                                  const int* __restrict__ rowptr,
                                                  const int* __restrict__ col,
                                                  float* __restrict__ out, int n, int nt) {
    constexpr int ST2 = 72, KS = 2;
    __shared__ unsigned short Zs[2][32 * ST2];

    int t = threadIdx.x;
    int lane = t & 63, wave = t >> 6, quad = lane >> 4, l15 = lane & 15;

    bf8_t breg[KS];
    {
        const unsigned short* bp = WTo + (size_t)(wave * 16 + l15) * 64 + quad * 8;
#pragma unroll
        for (int s = 0; s < KS; s++) breg[s] = *(const bf8_t*)(bp + s * 32);
    }
    int colg = wave * 16 + l15;
    float bias = (colg < 32) ? bmu[colg] : bls[colg - 32];
    float* dstc = (colg < 32) ? (out + colg) : (out + (size_t)n * 32 + (colg - 32));

    int gl = t >> 3;          // tile-local row 0..31
    int c  = (t & 7) * 8;

    int p = 0;
    for (int tile = blockIdx.x; tile < nt; tile += gridDim.x, p ^= 1) {
        int tbase = tile * 32;
        {
            int g = tbase + gl; if (g > n - 1) g = n - 1;
            int r0 = rowptr[g], r1 = rowptr[g + 1];
            float acc[8];
            {
                bf8_t v = *(const bf8_t*)(H2s + (size_t)g * 64 + c);
#pragma unroll
                for (int j = 0; j < 8; j++) acc[j] = bf2f((unsigned short)v[j]);
            }
            int e = r0;
            for (; e + 4 <= r1; e += 4) {
                int s0 = col[e], s1 = col[e + 1], s2 = col[e + 2], s3 = col[e + 3];
                bf8_t v0 = *(const bf8_t*)(H2s + (size_t)s0 * 64 + c);
                bf8_t v1 = *(const bf8_t*)(H2s + (size_t)s1 * 64 + c);
                bf8_t v2 = *(const bf8_t*)(H2s + (size_t)s2 * 64 + c);
                bf8_t v3 = *(const bf8_t*)(H2s + (size_t)s3 * 64 + c);
#pragma unroll
                for (int j = 0; j < 8; j++)
                    acc[j] += (bf2f((unsigned short)v0[j]) + bf2f((unsigned short)v1[j]))
                            + (bf2f((unsigned short)v2[j]) + bf2f((unsigned short)v3[j]));
            }
            for (; e < r1; ++e) {
                int s = col[e];
                bf8_t v = *(const bf8_t*)(H2s + (size_t)s * 64 + c);
#pragma unroll
                for (int j = 0; j < 8; j++) acc[j] += bf2f((unsigned short)v[j]);
            }
            float dg = dis[g];
            us8_t o;
#pragma unroll
            for (int j = 0; j < 8; j++) o[j] = f2bf(dg * acc[j]);
            *(us8_t*)(&Zs[p][gl * ST2 + c]) = o;
        }
        __syncthreads();

#pragma unroll
        for (int st = 0; st < 2; st++) {
            const unsigned short* apl = &Zs[p][(st * 16 + l15) * ST2 + quad * 8];
            bf8_t a[KS];
#pragma unroll
            for (int s = 0; s < KS; s++) a[s] = *(const bf8_t*)(apl + s * 32);
            f4_t acc = {0.f, 0.f, 0.f, 0.f};
#pragma unroll
            for (int s = 0; s < KS; s++)
                acc = __builtin_amdgcn_mfma_f32_16x16x32_bf16(a[s], breg[s], acc, 0, 0, 0);
            int row = tbase + st * 16 + quad * 4;
#pragma unroll
            for (int r = 0; r < 4; r++) {
                if (row + r < n) dstc[(size_t)(row + r) * 32] = acc[r] + bias;
            }
        }
    }
}

// ---------------- launch ----------------

extern "C" void kernel_launch(void* const* d_in, const int* in_sizes, int n_in,
                              void* d_out, int out_size, void* d_ws, size_t ws_size,
                              hipStream_t stream) {
    const float* x   = (const float*)d_in[0];
    const int*   ei  = (const int*)d_in[1];
    const float* W1  = (const float*)d_in[2];
    const float* b1  = (const float*)d_in[3];
    const float* Wr1 = (const float*)d_in[4];
    const float* W2  = (const float*)d_in[5];
    const float* b2  = (const float*)d_in[6];
    const float* Wr2 = (const float*)d_in[7];
    const float* Wmu = (const float*)d_in[8];
    const float* bmu = (const float*)d_in[9];
    const float* Wls = (const float*)d_in[10];
    const float* bls = (const float*)d_in[11];
    float* out = (float*)d_out;

    const int IN = 128, L1F = 96, L2F = 64;
    const int N = in_sizes[0] / IN;
    const int E = in_sizes[1] / 2;

    char* ws = (char*)d_ws;
    size_t off = 0;
    auto alloc = [&](size_t b) { size_t r = off; off += (b + 255) & ~(size_t)255; return r; };

    const int nb = (N + TPB - 1) / TPB;
    int*   cnt  = (int*)(ws + alloc((size_t)N * 4));
    int*   bsum = (int*)(ws + alloc((size_t)nb * 4));
    int*   rowp = (int*)(ws + alloc((size_t)(N + 1) * 4));
    int*   curs = (int*)(ws + alloc((size_t)N * 4));
    int*   col  = (int*)(ws + alloc((size_t)E * 4));
    float* dinv = (float*)(ws + alloc((size_t)N * 4));
    float* dis  = (float*)(ws + alloc((size_t)N * 4));
    unsigned short* T1  = (unsigned short*)(ws + alloc((size_t)IN  * L1F * 2));
    unsigned short* Tr1 = (unsigned short*)(ws + alloc((size_t)IN  * L1F * 2));
    unsigned short* T2  = (unsigned short*)(ws + alloc((size_t)L1F * L2F * 2));
    unsigned short* Tr2 = (unsigned short*)(ws + alloc((size_t)L1F * L2F * 2));
    unsigned short* Tmu = (unsigned short*)(ws + alloc((size_t)L2F * 32 * 2));
    unsigned short* Tls = (unsigned short*)(ws + alloc((size_t)L2F * 32 * 2));
    unsigned short* Y1  = (unsigned short*)(ws + alloc((size_t)N * L1F * 2));  // N x 96 bf16
    unsigned short* R1  = (unsigned short*)(ws + alloc((size_t)N * L1F * 2));  // N x 96 bf16
    unsigned short* Y2  = (unsigned short*)(ws + alloc((size_t)N * L2F * 2));  // N x 64 bf16
    unsigned short* R2  = (unsigned short*)(ws + alloc((size_t)N * L2F * 2));  // N x 64 bf16
    unsigned short* H2s = (unsigned short*)(ws + alloc((size_t)N * L2F * 2));  // dis-scaled h2
    (void)Tr1; (void)Tr2; (void)Tls;

    hipMemsetAsync(cnt, 0, (size_t)N * 4, stream);

    dim3 eg((E + TPB - 1) / TPB);
    k_count<<<eg, TPB, 0, stream>>>(ei, E, cnt);
    k_scan12<<<1, 512, 0, stream>>>(cnt, N, nb, bsum);
    k_rowptr<<<nb, TPB, 0, stream>>>(cnt, bsum, N, E, rowp, curs, dinv, dis);
    k_fill<<<eg, TPB, 0, stream>>>(ei, E, curs, col);

    k_wconv<<<dim3(48, 6), TPB, 0, stream>>>(W1, Wr1, W2, Wr2, Wmu, Wls,
                                             T1, Tr1, T2, Tr2, Tmu, Tls);

    // layer 1 GEMM: [Y1|R1] = x @ [W1|Wr1], split buffers (gather set 38.4 -> 19.2 MB)
    const int nt64 = (N + 63) / 64;
    k_gemm3s<128, 192, 96, true><<<768, TPB, 0, stream>>>(x, T1, Y1, R1, N, nt64);

    // fused: agg(layer1) + GEMM(layer2) -> Y2|R2
    const int nt16 = (N + 15) / 16;
    k_fuse1<<<2048, TPB, 0, stream>>>(Y1, R1, T2, b1, dinv, rowp, col, Y2, R2, N, nt16);

    // layer 2 aggregation: H2s = dis * relu(dinv*agg(Y2) + R2 + b2)
    k_aggc2<<<(N + 31) / 32, TPB, 0, stream>>>(Y2, R2, b2, dinv, dis, rowp, col, H2s, N);

    // fused: head aggregation + head GEMM -> out
    const int nt32 = (N + 31) / 32;
    k_fuse2<<<2048, TPB, 0, stream>>>(H2s, Tmu, bmu, bls, dis, rowp, col, out, N, nt32);
}

// Round 10
// 288.236 us; speedup vs baseline: 1.1113x; 1.0054x over previous
//
#include <hip/hip_runtime.h>

#define TPB 256

typedef __attribute__((ext_vector_type(8))) short          bf8_t;   // 8 x bf16 (4 VGPRs)
typedef __attribute__((ext_vector_type(8))) unsigned short us8_t;
typedef __attribute__((ext_vector_type(4))) float          f4_t;
typedef __attribute__((ext_vector_type(4))) unsigned short us4_t;
typedef __attribute__((ext_vector_type(4))) int            i4_t;

__device__ __forceinline__ unsigned short f2bf(float f) {
    union { float f; unsigned u; } v; v.f = f;
    unsigned r = v.u + 0x7FFFu + ((v.u >> 16) & 1u);   // round-to-nearest-even
    return (unsigned short)(r >> 16);
}
__device__ __forceinline__ float bf2f(unsigned short u) {
    union { unsigned u; float f; } v; v.u = (unsigned)u << 16; return v.f;
}

// ---------------- graph build (CSR by dst, rebuilt every call) ----------------

__global__ void k_count(const int* __restrict__ ei, int E, int* __restrict__ cnt) {
    int e = blockIdx.x * TPB + threadIdx.x;
    if (e < E) atomicAdd(&cnt[ei[E + e]], 1);
}

// fused block-sum + scan, int4-vectorized partial sums.
__global__ void k_scan12(const int* __restrict__ cnt, int n, int nb, int* __restrict__ bsum) {
    __shared__ int s[512];
    int t = threadIdx.x;
    int sum = 0;
    if (t < nb) {
        int base = t * TPB;
        int end = base + TPB; if (end > n) end = n;
        int i = base;
        for (; i + 4 <= end; i += 4) {
            i4_t v = *(const i4_t*)(cnt + i);
            sum += v.x + v.y + v.z + v.w;
        }
        for (; i < end; i++) sum += cnt[i];
    }
    s[t] = sum; __syncthreads();
    for (int off = 1; off < 512; off <<= 1) {
        int x = (t >= off) ? s[t - off] : 0;
        __syncthreads();
        s[t] += x;
        __syncthreads();
    }
    if (t < nb) bsum[t] = s[t] - sum;   // exclusive
}

__global__ void k_rowptr(const int* __restrict__ cnt, const int* __restrict__ bsum, int n, int E,
                         int* __restrict__ rowptr, int* __restrict__ cursor,
                         float* __restrict__ dinv, float* __restrict__ dis) {
    __shared__ int s[TPB];
    int t = threadIdx.x, i = blockIdx.x * TPB + t;
    int v = (i < n) ? cnt[i] : 0;
    s[t] = v; __syncthreads();
    for (int off = 1; off < TPB; off <<= 1) {
        int x = (t >= off) ? s[t - off] : 0;
        __syncthreads();
        s[t] += x;
        __syncthreads();
    }
    if (i < n) {
        int start = bsum[blockIdx.x] + s[t] - v;
        rowptr[i] = start;
        cursor[i] = start;
        float d = (float)(v + 1);      // + self loop; deg >= 1 always
        dinv[i] = 1.0f / d;
        dis[i]  = rsqrtf(d);
    }
    if (i == 0) rowptr[n] = E;
}

__global__ void k_fill(const int* __restrict__ ei, int E,
                       int* __restrict__ cursor, int* __restrict__ col) {
    int e = blockIdx.x * TPB + threadIdx.x;
    if (e < E) {
        int src = ei[e], dst = ei[E + e];
        int p = atomicAdd(&cursor[dst], 1);
        col[p] = src;
    }
}

// ---------------- weight transpose+convert: T[m*K + k] = bf16(W[k*M + m]) ----------------
__global__ void k_wconv(const float* W1, const float* Wr1, const float* W2, const float* Wr2,
                        const float* Wmu, const float* Wls,
                        unsigned short* T1, unsigned short* Tr1, unsigned short* T2,
                        unsigned short* Tr2, unsigned short* Tmu, unsigned short* Tls) {
    const float* W; unsigned short* T; int K, M;
    switch (blockIdx.y) {
        case 0: W = W1;  T = T1;  K = 128; M = 96; break;
        case 1: W = Wr1; T = Tr1; K = 128; M = 96; break;
        case 2: W = W2;  T = T2;  K = 96;  M = 64; break;
        case 3: W = Wr2; T = Tr2; K = 96;  M = 64; break;
        case 4: W = Wmu; T = Tmu; K = 64;  M = 32; break;
        default:W = Wls; T = Tls; K = 64;  M = 32; break;
    }
    int idx = blockIdx.x * TPB + threadIdx.x;
    if (idx < K * M) {
        int m = idx / K, k = idx % K;
        T[idx] = f2bf(W[k * M + m]);
    }
}

// ---------------- MFMA GEMM v9: 512-thread blocks, 8 waves/CU (2x r0) ----------------------
// r0 structure pinned at 4 waves/CU (52 KB LDS -> 1 block/CU x 4 waves); every other knob
// (traffic, ILP, stores, occupancy-via-split) measured neutral or worse. This variant keeps
// the identical B-stage + per-row store pattern (amp-1.0 proven) but uses 512 threads:
// 8 waves share the one LDS B copy, each wave owns a 16-row tile -> 2x wave-level latency
// hiding at constant traffic. grid 256 = exactly 1 block/CU.
template <int K, int M, bool AF32>
__global__ __launch_bounds__(512, 1) void k_gemm9(const void* __restrict__ Av,
                                                  const unsigned short* __restrict__ WT,
                                                  unsigned short* __restrict__ Yb,
                                                  int n, int nt) {
    constexpr int KS = K / 32;
    constexpr int ST = K + 8;
    __shared__ unsigned short Bs[M * ST];
    for (int i = threadIdx.x * 8; i < M * K; i += 512 * 8) {
        int m = i / K, k = i - m * K;
        *(us8_t*)(Bs + m * ST + k) = *(const us8_t*)(WT + i);
    }
    __syncthreads();

    int lane = threadIdx.x & 63;
    int wave = threadIdx.x >> 6;     // 0..7
    int quad = lane >> 4;
    int l15  = lane & 15;

    for (int t = blockIdx.x * 8 + wave; t < nt; t += gridDim.x * 8) {
        int tbase = t * 16;
        int rA = tbase + l15; if (rA > n - 1) rA = n - 1;

        bf8_t a[KS];
        if (AF32) {
            const float* ap = (const float*)Av + (size_t)rA * K + quad * 8;
#pragma unroll
            for (int s = 0; s < KS; s++) {
                f4_t lo = *(const f4_t*)(ap + s * 32);
                f4_t hi = *(const f4_t*)(ap + s * 32 + 4);
                bf8_t tv;
                tv[0] = (short)f2bf(lo.x); tv[1] = (short)f2bf(lo.y);
                tv[2] = (short)f2bf(lo.z); tv[3] = (short)f2bf(lo.w);
                tv[4] = (short)f2bf(hi.x); tv[5] = (short)f2bf(hi.y);
                tv[6] = (short)f2bf(hi.z); tv[7] = (short)f2bf(hi.w);
                a[s] = tv;
            }
        } else {
            const unsigned short* ap = (const unsigned short*)Av + (size_t)rA * K + quad * 8;
#pragma unroll
            for (int s = 0; s < KS; s++) a[s] = *(const bf8_t*)(ap + s * 32);
        }

        int row = tbase + quad * 4;
#pragma unroll
        for (int ct = 0; ct < M / 16; ct++) {
            const unsigned short* bp = Bs + (ct * 16 + l15) * ST + quad * 8;
            f4_t acc = {0.f, 0.f, 0.f, 0.f};
#pragma unroll
            for (int s = 0; s < KS; s++) {
                bf8_t b = *(const bf8_t*)(bp + s * 32);
                acc = __builtin_amdgcn_mfma_f32_16x16x32_bf16(a[s], b, acc, 0, 0, 0);
            }
            int colg = ct * 16 + l15;
#pragma unroll
            for (int r = 0; r < 4; r++) {
                if (row + r < n) Yb[(size_t)(row + r) * M + colg] = f2bf(acc[r]);
            }
        }
    }
}

// ---------------- fuse1 (r7-best body): agg(layer1) + GEMM(layer2) per 16-row tile ----------
__global__ __launch_bounds__(TPB, 4) void k_fuse1(const unsigned short* __restrict__ AB,
                                                  const unsigned short* __restrict__ WT2,
                                                  const float* __restrict__ bias,
                                                  const float* __restrict__ dinv,
                                                  const int* __restrict__ rowptr,
                                                  const int* __restrict__ col,
                                                  unsigned short* __restrict__ AB2,
                                                  int n, int nt) {
    constexpr int LDA = 192, MF = 96, ST1 = 104, KS = 3, M2 = 128;
    __shared__ unsigned short Hs[2][16 * ST1];

    int t = threadIdx.x;
    int lane = t & 63, wave = t >> 6, quad = lane >> 4, l15 = lane & 15;

    bf8_t breg[2][KS];
#pragma unroll
    for (int j = 0; j < 2; j++) {
        const unsigned short* bp = WT2 + (size_t)((wave * 2 + j) * 16 + l15) * 96 + quad * 8;
#pragma unroll
        for (int s = 0; s < KS; s++) breg[j][s] = *(const bf8_t*)(bp + s * 32);
    }

    int gl = t >> 4;          // tile-local row 0..15
    int cg = t & 15;          // col-group; active if cg < 12
    int c  = cg * 8;
    bool p1act = (c < MF);

    int p = 0;
    for (int tile = blockIdx.x; tile < nt; tile += gridDim.x, p ^= 1) {
        int tbase = tile * 16;
        if (p1act) {
            int g = tbase + gl; if (g > n - 1) g = n - 1;
            int r0 = rowptr[g], r1 = rowptr[g + 1];
            float acc[8];
            {
                bf8_t v = *(const bf8_t*)(AB + (size_t)g * LDA + c);
#pragma unroll
                for (int j = 0; j < 8; j++) acc[j] = bf2f((unsigned short)v[j]);
            }
            int e = r0;
            for (; e + 4 <= r1; e += 4) {
                int s0 = col[e], s1 = col[e + 1], s2 = col[e + 2], s3 = col[e + 3];
                bf8_t v0 = *(const bf8_t*)(AB + (size_t)s0 * LDA + c);
                bf8_t v1 = *(const bf8_t*)(AB + (size_t)s1 * LDA + c);
                bf8_t v2 = *(const bf8_t*)(AB + (size_t)s2 * LDA + c);
                bf8_t v3 = *(const bf8_t*)(AB + (size_t)s3 * LDA + c);
#pragma unroll
                for (int j = 0; j < 8; j++)
                    acc[j] += (bf2f((unsigned short)v0[j]) + bf2f((unsigned short)v1[j]))
                            + (bf2f((unsigned short)v2[j]) + bf2f((unsigned short)v3[j]));
            }
            for (; e < r1; ++e) {
                int s = col[e];
                bf8_t v = *(const bf8_t*)(AB + (size_t)s * LDA + c);
#pragma unroll
                for (int j = 0; j < 8; j++) acc[j] += bf2f((unsigned short)v[j]);
            }
            float di = dinv[g];
            bf8_t rr = *(const bf8_t*)(AB + (size_t)g * LDA + MF + c);
            us8_t o;
#pragma unroll
            for (int j = 0; j < 8; j++)
                o[j] = f2bf(fmaxf(acc[j] * di + bf2f((unsigned short)rr[j]) + bias[c + j], 0.f));
            *(us8_t*)(&Hs[p][gl * ST1 + c]) = o;
        }
        __syncthreads();

        // phase 2: 16 x 128 GEMM from LDS h1 tile
        int row = tbase + quad * 4;
#pragma unroll
        for (int j = 0; j < 2; j++) {
            const unsigned short* apl = &Hs[p][l15 * ST1 + quad * 8];
            f4_t acc2 = {0.f, 0.f, 0.f, 0.f};
#pragma unroll
            for (int s = 0; s < KS; s++) {
                bf8_t a = *(const bf8_t*)(apl + s * 32);
                acc2 = __builtin_amdgcn_mfma_f32_16x16x32_bf16(a, breg[j][s], acc2, 0, 0, 0);
            }
            int colg = (wave * 2 + j) * 16 + l15;
#pragma unroll
            for (int r = 0; r < 4; r++) {
                if (row + r < n) AB2[(size_t)(row + r) * M2 + colg] = f2bf(acc2[r]);
            }
        }
    }
}

// ---------------- aggc (r7 body, layer 2): H2s = dis * relu(dinv*agg(y2) + r2 + b2) ---------
template <int MF, int GRP, bool SCALE>
__global__ __launch_bounds__(TPB) void k_aggc(const unsigned short* __restrict__ AB,
                                              const float* __restrict__ bias,
                                              const float* __restrict__ dinv,
                                              const float* __restrict__ dis,
                                              const int* __restrict__ rowptr,
                                              const int* __restrict__ col,
                                              unsigned short* __restrict__ Hb, int n) {
    constexpr int LD = 2 * MF;
    int g = blockIdx.x * (TPB / GRP) + threadIdx.x / GRP;
    int l = threadIdx.x & (GRP - 1);
    if (g >= n) return;
    int c = l * 8;
    if (c >= MF) return;
    int r0 = rowptr[g], r1 = rowptr[g + 1];
    float acc[8];
    {
        bf8_t v = *(const bf8_t*)(AB + (size_t)g * LD + c);
#pragma unroll
        for (int j = 0; j < 8; j++) acc[j] = bf2f((unsigned short)v[j]);
    }
    int e = r0;
    for (; e + 4 <= r1; e += 4) {
        int s0 = col[e], s1 = col[e + 1], s2 = col[e + 2], s3 = col[e + 3];
        bf8_t v0 = *(const bf8_t*)(AB + (size_t)s0 * LD + c);
        bf8_t v1 = *(const bf8_t*)(AB + (size_t)s1 * LD + c);
        bf8_t v2 = *(const bf8_t*)(AB + (size_t)s2 * LD + c);
        bf8_t v3 = *(const bf8_t*)(AB + (size_t)s3 * LD + c);
#pragma unroll
        for (int j = 0; j < 8; j++)
            acc[j] += (bf2f((unsigned short)v0[j]) + bf2f((unsigned short)v1[j]))
                    + (bf2f((unsigned short)v2[j]) + bf2f((unsigned short)v3[j]));
    }
    for (; e < r1; ++e) {
        int s = col[e];
        bf8_t v = *(const bf8_t*)(AB + (size_t)s * LD + c);
#pragma unroll
        for (int j = 0; j < 8; j++) acc[j] += bf2f((unsigned short)v[j]);
    }
    float di = dinv[g];
    float sc = SCALE ? dis[g] : 1.0f;
    bf8_t rr = *(const bf8_t*)(AB + (size_t)g * LD + MF + c);
    us8_t o;
#pragma unroll
    for (int j = 0; j < 8; j++) {
        float h = fmaxf(acc[j] * di + bf2f((unsigned short)rr[j]) + bias[c + j], 0.f);
        o[j] = f2bf(SCALE ? sc * h : h);
    }
    *(us8_t*)(Hb + (size_t)g * MF + c) = o;
}

// ---------------- fuse2 (r7-best body): head agg + head GEMM per 32-row tile ----------------
__global__ __launch_bounds__(TPB, 4) void k_fuse2(const unsigned short* __restrict__ H2s,
                                                  const unsigned short* __restrict__ WTo,
                                                  const float* __restrict__ bmu,
                                                  const float* __restrict__ bls,
                                                  const float* __restrict__ dis,
                                                  const int* __restrict__ rowptr,
                                                  const int* __restrict__ col,
                                                  float* __restrict__ out, int n, int nt) {
    constexpr int ST2 = 72, KS = 2;
    __shared__ unsigned short Zs[2][32 * ST2];

    int t = threadIdx.x;
    int lane = t & 63, wave = t >> 6, quad = lane >> 4, l15 = lane & 15;

    bf8_t breg[KS];
    {
        const unsigned short* bp = WTo + (size_t)(wave * 16 + l15) * 64 + quad * 8;
#pragma unroll
        for (int s = 0; s < KS; s++) breg[s] = *(const bf8_t*)(bp + s * 32);
    }
    int colg = wave * 16 + l15;
    float bias = (colg < 32) ? bmu[colg] : bls[colg - 32];
    float* dstc = (colg < 32) ? (out + colg) : (out + (size_t)n * 32 + (colg - 32));

    int gl = t >> 3;          // tile-local row 0..31
    int c  = (t & 7) * 8;

    int p = 0;
    for (int tile = blockIdx.x; tile < nt; tile += gridDim.x, p ^= 1) {
        int tbase = tile * 32;
        {
            int g = tbase + gl; if (g > n - 1) g = n - 1;
            int r0 = rowptr[g], r1 = rowptr[g + 1];
            float acc[8];
            {
                bf8_t v = *(const bf8_t*)(H2s + (size_t)g * 64 + c);
#pragma unroll
                for (int j = 0; j < 8; j++) acc[j] = bf2f((unsigned short)v[j]);
            }
            int e = r0;
            for (; e + 4 <= r1; e += 4) {
                int s0 = col[e], s1 = col[e + 1], s2 = col[e + 2], s3 = col[e + 3];
                bf8_t v0 = *(const bf8_t*)(H2s + (size_t)s0 * 64 + c);
                bf8_t v1 = *(const bf8_t*)(H2s + (size_t)s1 * 64 + c);
                bf8_t v2 = *(const bf8_t*)(H2s + (size_t)s2 * 64 + c);
                bf8_t v3 = *(const bf8_t*)(H2s + (size_t)s3 * 64 + c);
#pragma unroll
                for (int j = 0; j < 8; j++)
                    acc[j] += (bf2f((unsigned short)v0[j]) + bf2f((unsigned short)v1[j]))
                            + (bf2f((unsigned short)v2[j]) + bf2f((unsigned short)v3[j]));
            }
            for (; e < r1; ++e) {
                int s = col[e];
                bf8_t v = *(const bf8_t*)(H2s + (size_t)s * 64 + c);
#pragma unroll
                for (int j = 0; j < 8; j++) acc[j] += bf2f((unsigned short)v[j]);
            }
            float dg = dis[g];
            us8_t o;
#pragma unroll
            for (int j = 0; j < 8; j++) o[j] = f2bf(dg * acc[j]);
            *(us8_t*)(&Zs[p][gl * ST2 + c]) = o;
        }
        __syncthreads();

#pragma unroll
        for (int st = 0; st < 2; st++) {
            const unsigned short* apl = &Zs[p][(st * 16 + l15) * ST2 + quad * 8];
            bf8_t a[KS];
#pragma unroll
            for (int s = 0; s < KS; s++) a[s] = *(const bf8_t*)(apl + s * 32);
            f4_t acc = {0.f, 0.f, 0.f, 0.f};
#pragma unroll
            for (int s = 0; s < KS; s++)
                acc = __builtin_amdgcn_mfma_f32_16x16x32_bf16(a[s], breg[s], acc, 0, 0, 0);
            int row = tbase + st * 16 + quad * 4;
#pragma unroll
            for (int r = 0; r < 4; r++) {
                if (row + r < n) dstc[(size_t)(row + r) * 32] = acc[r] + bias;
            }
        }
    }
}

// ---------------- launch ----------------

extern "C" void kernel_launch(void* const* d_in, const int* in_sizes, int n_in,
                              void* d_out, int out_size, void* d_ws, size_t ws_size,
                              hipStream_t stream) {
    const float* x   = (const float*)d_in[0];
    const int*   ei  = (const int*)d_in[1];
    const float* W1  = (const float*)d_in[2];
    const float* b1  = (const float*)d_in[3];
    const float* Wr1 = (const float*)d_in[4];
    const float* W2  = (const float*)d_in[5];
    const float* b2  = (const float*)d_in[6];
    const float* Wr2 = (const float*)d_in[7];
    const float* Wmu = (const float*)d_in[8];
    const float* bmu = (const float*)d_in[9];
    const float* Wls = (const float*)d_in[10];
    const float* bls = (const float*)d_in[11];
    float* out = (float*)d_out;

    const int IN = 128, L1F = 96, L2F = 64;
    const int N = in_sizes[0] / IN;
    const int E = in_sizes[1] / 2;

    char* ws = (char*)d_ws;
    size_t off = 0;
    auto alloc = [&](size_t b) { size_t r = off; off += (b + 255) & ~(size_t)255; return r; };

    const int nb = (N + TPB - 1) / TPB;
    int*   cnt  = (int*)(ws + alloc((size_t)N * 4));
    int*   bsum = (int*)(ws + alloc((size_t)nb * 4));
    int*   rowp = (int*)(ws + alloc((size_t)(N + 1) * 4));
    int*   curs = (int*)(ws + alloc((size_t)N * 4));
    int*   col  = (int*)(ws + alloc((size_t)E * 4));
    float* dinv = (float*)(ws + alloc((size_t)N * 4));
    float* dis  = (float*)(ws + alloc((size_t)N * 4));
    unsigned short* T1  = (unsigned short*)(ws + alloc((size_t)IN  * L1F * 2));
    unsigned short* Tr1 = (unsigned short*)(ws + alloc((size_t)IN  * L1F * 2));
    unsigned short* T2  = (unsigned short*)(ws + alloc((size_t)L1F * L2F * 2));
    unsigned short* Tr2 = (unsigned short*)(ws + alloc((size_t)L1F * L2F * 2));
    unsigned short* Tmu = (unsigned short*)(ws + alloc((size_t)L2F * 32 * 2));
    unsigned short* Tls = (unsigned short*)(ws + alloc((size_t)L2F * 32 * 2));
    unsigned short* AB1 = (unsigned short*)(ws + alloc((size_t)N * 2 * L1F * 2)); // N x 192 bf16
    unsigned short* AB2 = (unsigned short*)(ws + alloc((size_t)N * 2 * L2F * 2)); // N x 128 bf16
    unsigned short* H2s = (unsigned short*)(ws + alloc((size_t)N * L2F * 2));     // dis-scaled h2
    (void)Tr1; (void)Tr2; (void)Tls;

    hipMemsetAsync(cnt, 0, (size_t)N * 4, stream);

    dim3 eg((E + TPB - 1) / TPB);
    k_count<<<eg, TPB, 0, stream>>>(ei, E, cnt);
    k_scan12<<<1, 512, 0, stream>>>(cnt, N, nb, bsum);
    k_rowptr<<<nb, TPB, 0, stream>>>(cnt, bsum, N, E, rowp, curs, dinv, dis);
    k_fill<<<eg, TPB, 0, stream>>>(ei, E, curs, col);

    k_wconv<<<dim3(48, 6), TPB, 0, stream>>>(W1, Wr1, W2, Wr2, Wmu, Wls,
                                             T1, Tr1, T2, Tr2, Tmu, Tls);

    // layer 1 GEMM: AB1 = x @ [W1|Wr1], 512-thread blocks (8 waves/CU, 2x r0), grid = 1/CU
    const int nt16 = (N + 15) / 16;
    k_gemm9<128, 192, true><<<256, 512, 0, stream>>>(x, T1, AB1, N, nt16);

    // fused: agg(layer1) + GEMM(layer2) -> AB2
    k_fuse1<<<2048, TPB, 0, stream>>>(AB1, T2, b1, dinv, rowp, col, AB2, N, nt16);

    // layer 2 aggregation: H2s = dis * relu(dinv*agg + r + b2)
    k_aggc<64, 8, true><<<(N + 31) / 32, TPB, 0, stream>>>(AB2, b2, dinv, dis, rowp, col, H2s, N);

    // fused: head aggregation + head GEMM -> out
    const int nt32 = (N + 31) / 32;
    k_fuse2<<<2048, TPB, 0, stream>>>(H2s, Tmu, bmu, bls, dis, rowp, col, out, N, nt32);
}

// Round 11
// 282.263 us; speedup vs baseline: 1.1348x; 1.0212x over previous
//
#include <hip/hip_runtime.h>

#define TPB 256

typedef __attribute__((ext_vector_type(8))) short          bf8_t;   // 8 x bf16 (4 VGPRs)
typedef __attribute__((ext_vector_type(8))) unsigned short us8_t;
typedef __attribute__((ext_vector_type(4))) float          f4_t;
typedef __attribute__((ext_vector_type(4))) unsigned short us4_t;

__device__ __forceinline__ unsigned short f2bf(float f) {
    union { float f; unsigned u; } v; v.f = f;
    unsigned r = v.u + 0x7FFFu + ((v.u >> 16) & 1u);   // round-to-nearest-even
    return (unsigned short)(r >> 16);
}
__device__ __forceinline__ float bf2f(unsigned short u) {
    union { unsigned u; float f; } v; v.u = (unsigned)u << 16; return v.f;
}

// ---------------- graph build (CSR by dst, rebuilt every call) ----------------

__global__ void k_count(const int* __restrict__ ei, int E, int* __restrict__ cnt) {
    int e = blockIdx.x * TPB + threadIdx.x;
    if (e < E) atomicAdd(&cnt[ei[E + e]], 1);
}

__global__ void k_blocksum(const int* __restrict__ cnt, int n, int* __restrict__ bsum) {
    __shared__ int s[TPB];
    int t = threadIdx.x, i = blockIdx.x * TPB + t;
    s[t] = (i < n) ? cnt[i] : 0;
    __syncthreads();
    for (int off = TPB / 2; off > 0; off >>= 1) {
        if (t < off) s[t] += s[t + off];
        __syncthreads();
    }
    if (t == 0) bsum[blockIdx.x] = s[0];
}

__global__ void k_scan_bsum(int* __restrict__ bsum, int nb) {
    __shared__ int s[512];
    int t = threadIdx.x;
    int v = (t < nb) ? bsum[t] : 0;
    s[t] = v; __syncthreads();
    for (int off = 1; off < 512; off <<= 1) {
        int x = (t >= off) ? s[t - off] : 0;
        __syncthreads();
        s[t] += x;
        __syncthreads();
    }
    if (t < nb) bsum[t] = s[t] - v;   // exclusive block offsets
}

__global__ void k_rowptr(const int* __restrict__ cnt, const int* __restrict__ bsum, int n, int E,
                         int* __restrict__ rowptr, int* __restrict__ cursor,
                         float* __restrict__ dinv, float* __restrict__ dis) {
    __shared__ int s[TPB];
    int t = threadIdx.x, i = blockIdx.x * TPB + t;
    int v = (i < n) ? cnt[i] : 0;
    s[t] = v; __syncthreads();
    for (int off = 1; off < TPB; off <<= 1) {
        int x = (t >= off) ? s[t - off] : 0;
        __syncthreads();
        s[t] += x;
        __syncthreads();
    }
    if (i < n) {
        int start = bsum[blockIdx.x] + s[t] - v;
        rowptr[i] = start;
        cursor[i] = start;
        float d = (float)(v + 1);      // + self loop; deg >= 1 always
        dinv[i] = 1.0f / d;
        dis[i]  = rsqrtf(d);
    }
    if (i == 0) rowptr[n] = E;
}

__global__ void k_fill(const int* __restrict__ ei, int E,
                       int* __restrict__ cursor, int* __restrict__ col) {
    int e = blockIdx.x * TPB + threadIdx.x;
    if (e < E) {
        int src = ei[e], dst = ei[E + e];
        int p = atomicAdd(&cursor[dst], 1);
        col[p] = src;
    }
}

// ---------------- weight transpose+convert: T[m*K + k] = bf16(W[k*M + m]) ----------------
__global__ void k_wconv(const float* W1, const float* Wr1, const float* W2, const float* Wr2,
                        const float* Wmu, const float* Wls,
                        unsigned short* T1, unsigned short* Tr1, unsigned short* T2,
                        unsigned short* Tr2, unsigned short* Tmu, unsigned short* Tls) {
    const float* W; unsigned short* T; int K, M;
    switch (blockIdx.y) {
        case 0: W = W1;  T = T1;  K = 128; M = 96; break;
        case 1: W = Wr1; T = Tr1; K = 128; M = 96; break;
        case 2: W = W2;  T = T2;  K = 96;  M = 64; break;
        case 3: W = Wr2; T = Tr2; K = 96;  M = 64; break;
        case 4: W = Wmu; T = Tmu; K = 64;  M = 32; break;
        default:W = Wls; T = Tls; K = 64;  M = 32; break;
    }
    int idx = blockIdx.x * TPB + threadIdx.x;
    if (idx < K * M) {
        int m = idx / K, k = idx % K;
        T[idx] = f2bf(W[k * M + m]);
    }
}

// ---------------- MFMA GEMM (r0-measured-best form): LDS-staged B, 64-row tiles ------------
// Component ledger: 42.0 us / FETCH 25.4 / WRITE 37.5 (amp 1.0) at grid 768.
// Best of 7 structures tried (ILP/no-LDS/reg-B/512-thr all 42-49 -> latency floor).
template <int K, int M, bool AF32>
__global__ __launch_bounds__(TPB) void k_gemm3(const void* __restrict__ Av,
                                               const unsigned short* __restrict__ WT,
                                               unsigned short* __restrict__ Yb,
                                               int n, int nt) {
    constexpr int KS = K / 32;
    constexpr int ST = K + 8;
    __shared__ unsigned short Bs[M * ST];
    for (int i = threadIdx.x * 8; i < M * K; i += TPB * 8) {
        int m = i / K, k = i - m * K;
        *(us8_t*)(Bs + m * ST + k) = *(const us8_t*)(WT + i);
    }
    __syncthreads();

    int lane = threadIdx.x & 63;
    int wave = threadIdx.x >> 6;
    int quad = lane >> 4;
    int l15  = lane & 15;

    for (int tile = blockIdx.x; tile < nt; tile += gridDim.x) {
        int base = tile * 64 + wave * 16;
        int rA = base + l15; if (rA > n - 1) rA = n - 1;

        bf8_t a[KS];
        if (AF32) {
            const float* ap = (const float*)Av + (size_t)rA * K + quad * 8;
#pragma unroll
            for (int s = 0; s < KS; s++) {
                f4_t lo = *(const f4_t*)(ap + s * 32);
                f4_t hi = *(const f4_t*)(ap + s * 32 + 4);
                bf8_t t;
                t[0] = (short)f2bf(lo.x); t[1] = (short)f2bf(lo.y);
                t[2] = (short)f2bf(lo.z); t[3] = (short)f2bf(lo.w);
                t[4] = (short)f2bf(hi.x); t[5] = (short)f2bf(hi.y);
                t[6] = (short)f2bf(hi.z); t[7] = (short)f2bf(hi.w);
                a[s] = t;
            }
        } else {
            const unsigned short* ap = (const unsigned short*)Av + (size_t)rA * K + quad * 8;
#pragma unroll
            for (int s = 0; s < KS; s++) a[s] = *(const bf8_t*)(ap + s * 32);
        }

        int row = base + quad * 4;
#pragma unroll
        for (int ct = 0; ct < M / 16; ct++) {
            const unsigned short* bp = Bs + (ct * 16 + l15) * ST + quad * 8;
            f4_t acc = {0.f, 0.f, 0.f, 0.f};
#pragma unroll
            for (int s = 0; s < KS; s++) {
                bf8_t b = *(const bf8_t*)(bp + s * 32);
                acc = __builtin_amdgcn_mfma_f32_16x16x32_bf16(a[s], b, acc, 0, 0, 0);
            }
            int colg = ct * 16 + l15;
#pragma unroll
            for (int r = 0; r < 4; r++) {
                if (row + r < n) Yb[(size_t)(row + r) * M + colg] = f2bf(acc[r]);
            }
        }
    }
}

// ---------------- fuse1: ClusterGCN-agg(layer1) + GEMM(layer2) per 16-row tile --------------
// Gather = 600k edges x 192 B = 115 MB random fabric reads; measured 2.6-2.7 TB/s effective
// across 4 variants -> at the random-gather ceiling (line-granularity intrinsic).
__global__ __launch_bounds__(TPB, 4) void k_fuse1(const unsigned short* __restrict__ AB,
                                                  const unsigned short* __restrict__ WT2,
                                                  const float* __restrict__ bias,
                                                  const float* __restrict__ dinv,
                                                  const int* __restrict__ rowptr,
                                                  const int* __restrict__ col,
                                                  unsigned short* __restrict__ AB2,
                                                  int n, int nt) {
    constexpr int LDA = 192, MF = 96, ST1 = 104, KS = 3, M2 = 128;
    __shared__ unsigned short Hs[2][16 * ST1];

    int t = threadIdx.x;
    int lane = t & 63, wave = t >> 6, quad = lane >> 4, l15 = lane & 15;

    bf8_t breg[2][KS];
#pragma unroll
    for (int j = 0; j < 2; j++) {
        const unsigned short* bp = WT2 + (size_t)((wave * 2 + j) * 16 + l15) * 96 + quad * 8;
#pragma unroll
        for (int s = 0; s < KS; s++) breg[j][s] = *(const bf8_t*)(bp + s * 32);
    }

    int gl = t >> 4;          // tile-local row 0..15
    int cg = t & 15;          // col-group; active if cg < 12
    int c  = cg * 8;
    bool p1act = (c < MF);

    int p = 0;
    for (int tile = blockIdx.x; tile < nt; tile += gridDim.x, p ^= 1) {
        int tbase = tile * 16;
        if (p1act) {                                  // no early return: barrier below
            int g = tbase + gl; if (g > n - 1) g = n - 1;
            int r0 = rowptr[g], r1 = rowptr[g + 1];
            float acc[8];
            {
                bf8_t v = *(const bf8_t*)(AB + (size_t)g * LDA + c);
#pragma unroll
                for (int j = 0; j < 8; j++) acc[j] = bf2f((unsigned short)v[j]);
            }
            int e = r0;
            for (; e + 4 <= r1; e += 4) {
                int s0 = col[e], s1 = col[e + 1], s2 = col[e + 2], s3 = col[e + 3];
                bf8_t v0 = *(const bf8_t*)(AB + (size_t)s0 * LDA + c);
                bf8_t v1 = *(const bf8_t*)(AB + (size_t)s1 * LDA + c);
                bf8_t v2 = *(const bf8_t*)(AB + (size_t)s2 * LDA + c);
                bf8_t v3 = *(const bf8_t*)(AB + (size_t)s3 * LDA + c);
#pragma unroll
                for (int j = 0; j < 8; j++)
                    acc[j] += (bf2f((unsigned short)v0[j]) + bf2f((unsigned short)v1[j]))
                            + (bf2f((unsigned short)v2[j]) + bf2f((unsigned short)v3[j]));
            }
            for (; e < r1; ++e) {
                int s = col[e];
                bf8_t v = *(const bf8_t*)(AB + (size_t)s * LDA + c);
#pragma unroll
                for (int j = 0; j < 8; j++) acc[j] += bf2f((unsigned short)v[j]);
            }
            float di = dinv[g];
            bf8_t rr = *(const bf8_t*)(AB + (size_t)g * LDA + MF + c);
            us8_t o;
#pragma unroll
            for (int j = 0; j < 8; j++)
                o[j] = f2bf(fmaxf(acc[j] * di + bf2f((unsigned short)rr[j]) + bias[c + j], 0.f));
            *(us8_t*)(&Hs[p][gl * ST1 + c]) = o;
        }
        __syncthreads();

        // phase 2: 16 x 128 GEMM from LDS h1 tile
        int row = tbase + quad * 4;
#pragma unroll
        for (int j = 0; j < 2; j++) {
            const unsigned short* apl = &Hs[p][l15 * ST1 + quad * 8];
            f4_t acc2 = {0.f, 0.f, 0.f, 0.f};
#pragma unroll
            for (int s = 0; s < KS; s++) {
                bf8_t a = *(const bf8_t*)(apl + s * 32);
                acc2 = __builtin_amdgcn_mfma_f32_16x16x32_bf16(a, breg[j][s], acc2, 0, 0, 0);
            }
            int colg = (wave * 2 + j) * 16 + l15;
#pragma unroll
            for (int r = 0; r < 4; r++) {
                if (row + r < n) AB2[(size_t)(row + r) * M2 + colg] = f2bf(acc2[r]);
            }
        }
        // no trailing barrier: double buffer; next phase-1 writes Hs[p^1]
    }
}

// ---------------- aggc (standalone, layer 2): H2s = dis * relu(dinv*agg(y2) + r2 + b2) -------
template <int MF, int GRP, bool SCALE>
__global__ __launch_bounds__(TPB) void k_aggc(const unsigned short* __restrict__ AB,
                                              const float* __restrict__ bias,
                                              const float* __restrict__ dinv,
                                              const float* __restrict__ dis,
                                              const int* __restrict__ rowptr,
                                              const int* __restrict__ col,
                                              unsigned short* __restrict__ Hb, int n) {
    constexpr int LD = 2 * MF;
    int g = blockIdx.x * (TPB / GRP) + threadIdx.x / GRP;
    int l = threadIdx.x & (GRP - 1);
    if (g >= n) return;
    int c = l * 8;
    if (c >= MF) return;
    int r0 = rowptr[g], r1 = rowptr[g + 1];
    float acc[8];
    {
        bf8_t v = *(const bf8_t*)(AB + (size_t)g * LD + c);
#pragma unroll
        for (int j = 0; j < 8; j++) acc[j] = bf2f((unsigned short)v[j]);
    }
    int e = r0;
    for (; e + 4 <= r1; e += 4) {
        int s0 = col[e], s1 = col[e + 1], s2 = col[e + 2], s3 = col[e + 3];
        bf8_t v0 = *(const bf8_t*)(AB + (size_t)s0 * LD + c);
        bf8_t v1 = *(const bf8_t*)(AB + (size_t)s1 * LD + c);
        bf8_t v2 = *(const bf8_t*)(AB + (size_t)s2 * LD + c);
        bf8_t v3 = *(const bf8_t*)(AB + (size_t)s3 * LD + c);
#pragma unroll
        for (int j = 0; j < 8; j++)
            acc[j] += (bf2f((unsigned short)v0[j]) + bf2f((unsigned short)v1[j]))
                    + (bf2f((unsigned short)v2[j]) + bf2f((unsigned short)v3[j]));
    }
    for (; e < r1; ++e) {
        int s = col[e];
        bf8_t v = *(const bf8_t*)(AB + (size_t)s * LD + c);
#pragma unroll
        for (int j = 0; j < 8; j++) acc[j] += bf2f((unsigned short)v[j]);
    }
    float di = dinv[g];
    float sc = SCALE ? dis[g] : 1.0f;
    bf8_t rr = *(const bf8_t*)(AB + (size_t)g * LD + MF + c);
    us8_t o;
#pragma unroll
    for (int j = 0; j < 8; j++) {
        float h = fmaxf(acc[j] * di + bf2f((unsigned short)rr[j]) + bias[c + j], 0.f);
        o[j] = f2bf(SCALE ? sc * h : h);
    }
    *(us8_t*)(Hb + (size_t)g * MF + c) = o;
}

// ---------------- fuse2: head aggregation + head GEMM per 32-row tile -----------------------
__global__ __launch_bounds__(TPB, 4) void k_fuse2(const unsigned short* __restrict__ H2s,
                                                  const unsigned short* __restrict__ WTo,
                                                  const float* __restrict__ bmu,
                                                  const float* __restrict__ bls,
                                                  const float* __restrict__ dis,
                                                  const int* __restrict__ rowptr,
                                                  const int* __restrict__ col,
                                                  float* __restrict__ out, int n, int nt) {
    constexpr int ST2 = 72, KS = 2;
    __shared__ unsigned short Zs[2][32 * ST2];

    int t = threadIdx.x;
    int lane = t & 63, wave = t >> 6, quad = lane >> 4, l15 = lane & 15;

    bf8_t breg[KS];
    {
        const unsigned short* bp = WTo + (size_t)(wave * 16 + l15) * 64 + quad * 8;
#pragma unroll
        for (int s = 0; s < KS; s++) breg[s] = *(const bf8_t*)(bp + s * 32);
    }
    int colg = wave * 16 + l15;
    float bias = (colg < 32) ? bmu[colg] : bls[colg - 32];
    float* dstc = (colg < 32) ? (out + colg) : (out + (size_t)n * 32 + (colg - 32));

    int gl = t >> 3;          // tile-local row 0..31
    int c  = (t & 7) * 8;     // col 0..56 (all 256 threads active)

    int p = 0;
    for (int tile = blockIdx.x; tile < nt; tile += gridDim.x, p ^= 1) {
        int tbase = tile * 32;
        {
            int g = tbase + gl; if (g > n - 1) g = n - 1;
            int r0 = rowptr[g], r1 = rowptr[g + 1];
            float acc[8];
            {
                bf8_t v = *(const bf8_t*)(H2s + (size_t)g * 64 + c);
#pragma unroll
                for (int j = 0; j < 8; j++) acc[j] = bf2f((unsigned short)v[j]);
            }
            int e = r0;
            for (; e + 4 <= r1; e += 4) {
                int s0 = col[e], s1 = col[e + 1], s2 = col[e + 2], s3 = col[e + 3];
                bf8_t v0 = *(const bf8_t*)(H2s + (size_t)s0 * 64 + c);
                bf8_t v1 = *(const bf8_t*)(H2s + (size_t)s1 * 64 + c);
                bf8_t v2 = *(const bf8_t*)(H2s + (size_t)s2 * 64 + c);
                bf8_t v3 = *(const bf8_t*)(H2s + (size_t)s3 * 64 + c);
#pragma unroll
                for (int j = 0; j < 8; j++)
                    acc[j] += (bf2f((unsigned short)v0[j]) + bf2f((unsigned short)v1[j]))
                            + (bf2f((unsigned short)v2[j]) + bf2f((unsigned short)v3[j]));
            }
            for (; e < r1; ++e) {
                int s = col[e];
                bf8_t v = *(const bf8_t*)(H2s + (size_t)s * 64 + c);
#pragma unroll
                for (int j = 0; j < 8; j++) acc[j] += bf2f((unsigned short)v[j]);
            }
            float dg = dis[g];
            us8_t o;
#pragma unroll
            for (int j = 0; j < 8; j++) o[j] = f2bf(dg * acc[j]);
            *(us8_t*)(&Zs[p][gl * ST2 + c]) = o;
        }
        __syncthreads();

        // phase 2: two 16-row sub-tiles, ct = wave
#pragma unroll
        for (int st = 0; st < 2; st++) {
            const unsigned short* apl = &Zs[p][(st * 16 + l15) * ST2 + quad * 8];
            bf8_t a[KS];
#pragma unroll
            for (int s = 0; s < KS; s++) a[s] = *(const bf8_t*)(apl + s * 32);
            f4_t acc = {0.f, 0.f, 0.f, 0.f};
#pragma unroll
            for (int s = 0; s < KS; s++)
                acc = __builtin_amdgcn_mfma_f32_16x16x32_bf16(a[s], breg[s], acc, 0, 0, 0);
            int row = tbase + st * 16 + quad * 4;
#pragma unroll
            for (int r = 0; r < 4; r++) {
                if (row + r < n) dstc[(size_t)(row + r) * 32] = acc[r] + bias;
            }
        }
    }
}

// ---------------- launch ----------------

extern "C" void kernel_launch(void* const* d_in, const int* in_sizes, int n_in,
                              void* d_out, int out_size, void* d_ws, size_t ws_size,
                              hipStream_t stream) {
    const float* x   = (const float*)d_in[0];
    const int*   ei  = (const int*)d_in[1];
    const float* W1  = (const float*)d_in[2];
    const float* b1  = (const float*)d_in[3];
    const float* Wr1 = (const float*)d_in[4];
    const float* W2  = (const float*)d_in[5];
    const float* b2  = (const float*)d_in[6];
    const float* Wr2 = (const float*)d_in[7];
    const float* Wmu = (const float*)d_in[8];
    const float* bmu = (const float*)d_in[9];
    const float* Wls = (const float*)d_in[10];
    const float* bls = (const float*)d_in[11];
    float* out = (float*)d_out;

    const int IN = 128, L1F = 96, L2F = 64;
    const int N = in_sizes[0] / IN;
    const int E = in_sizes[1] / 2;

    char* ws = (char*)d_ws;
    size_t off = 0;
    auto alloc = [&](size_t b) { size_t r = off; off += (b + 255) & ~(size_t)255; return r; };

    const int nb = (N + TPB - 1) / TPB;
    int*   cnt  = (int*)(ws + alloc((size_t)N * 4));
    int*   bsum = (int*)(ws + alloc((size_t)nb * 4));
    int*   rowp = (int*)(ws + alloc((size_t)(N + 1) * 4));
    int*   curs = (int*)(ws + alloc((size_t)N * 4));
    int*   col  = (int*)(ws + alloc((size_t)E * 4));
    float* dinv = (float*)(ws + alloc((size_t)N * 4));
    float* dis  = (float*)(ws + alloc((size_t)N * 4));
    unsigned short* T1  = (unsigned short*)(ws + alloc((size_t)IN  * L1F * 2));
    unsigned short* Tr1 = (unsigned short*)(ws + alloc((size_t)IN  * L1F * 2));
    unsigned short* T2  = (unsigned short*)(ws + alloc((size_t)L1F * L2F * 2));
    unsigned short* Tr2 = (unsigned short*)(ws + alloc((size_t)L1F * L2F * 2));
    unsigned short* Tmu = (unsigned short*)(ws + alloc((size_t)L2F * 32 * 2));
    unsigned short* Tls = (unsigned short*)(ws + alloc((size_t)L2F * 32 * 2));
    unsigned short* AB1 = (unsigned short*)(ws + alloc((size_t)N * 2 * L1F * 2)); // N x 192 bf16
    unsigned short* AB2 = (unsigned short*)(ws + alloc((size_t)N * 2 * L2F * 2)); // N x 128 bf16
    unsigned short* H2s = (unsigned short*)(ws + alloc((size_t)N * L2F * 2));     // dis-scaled h2
    (void)Tr1; (void)Tr2; (void)Tls;

    hipMemsetAsync(cnt, 0, (size_t)N * 4, stream);

    dim3 eg((E + TPB - 1) / TPB);
    k_count<<<eg, TPB, 0, stream>>>(ei, E, cnt);
    k_blocksum<<<nb, TPB, 0, stream>>>(cnt, N, bsum);
    k_scan_bsum<<<1, 512, 0, stream>>>(bsum, nb);
    k_rowptr<<<nb, TPB, 0, stream>>>(cnt, bsum, N, E, rowp, curs, dinv, dis);
    k_fill<<<eg, TPB, 0, stream>>>(ei, E, curs, col);

    k_wconv<<<dim3(48, 6), TPB, 0, stream>>>(W1, Wr1, W2, Wr2, Wmu, Wls,
                                             T1, Tr1, T2, Tr2, Tmu, Tls);

    // layer 1 GEMM: AB1 = x @ [W1|Wr1]  (r0-measured-best config: 42 us, amp 1.0)
    const int nt64 = (N + 63) / 64;
    k_gemm3<128, 192, true><<<768, TPB, 0, stream>>>(x, T1, AB1, N, nt64);

    // fused: aggc(layer1) + GEMM(layer2) -> AB2   (Hb1 eliminated)
    const int nt16 = (N + 15) / 16;
    k_fuse1<<<2048, TPB, 0, stream>>>(AB1, T2, b1, dinv, rowp, col, AB2, N, nt16);

    // layer 2 aggregation: H2s = dis * relu(dinv*agg + r + b2)
    k_aggc<64, 8, true><<<(N + 31) / 32, TPB, 0, stream>>>(AB2, b2, dinv, dis, rowp, col, H2s, N);

    // fused: head aggregation + head GEMM -> out   (Zag eliminated)
    const int nt32 = (N + 31) / 32;
    k_fuse2<<<2048, TPB, 0, stream>>>(H2s, Tmu, bmu, bls, dis, rowp, col, out, N, nt32);
}